// Round 1
// baseline (491.899 us; speedup 1.0000x reference)
//
#include <hip/hip_runtime.h>
#include <math.h>

#define T_TOK 32768
#define DIM   2048
#define E_N   64
#define KP    2048   // padded reduction length (col 0 of wpad is zero)
#define KT    128    // k-tile staged in LDS
#define NT    (KP / KT)
#define BR    64     // rows per block

// ws layout (floats): [0, 131072) wpad[64][2048]; [131072, 131072+32768*64) logits
#define WS_WPAD_FLOATS (E_N * KP)

__device__ __forceinline__ void async16(const void* g, void* l) {
  __builtin_amdgcn_global_load_lds((const __attribute__((address_space(1))) void*)g,
                                   (__attribute__((address_space(3))) void*)l,
                                   16, 0, 0);
}

// ---------------- kernel 0: shift/pad weight ----------------
__global__ __launch_bounds__(256) void k_padw(const float* __restrict__ w,
                                              float* __restrict__ wpad) {
  int idx = blockIdx.x * 256 + threadIdx.x;   // 0 .. 64*2048-1
  int e = idx >> 11;
  int c = idx & 2047;
  wpad[idx] = (c == 0) ? 0.f : w[e * 2047 + (c - 1)];
}

// ---------------- kernel 1: logits = x[:,1:] @ W^T ----------------
// block: 256 thr = 4 waves; block tile 64 rows x 64 experts; wave owns 16 rows.
// lane = (eg<<2)|rg ; lane micro-tile: rows rg*4+{0..3}, experts eg*4+{0..3}
__global__ __launch_bounds__(256, 2) void k_logits(const float* __restrict__ x,
                                                   const float* __restrict__ wpad,
                                                   float* __restrict__ logits) {
  __shared__ float wt[E_N * KT];   // 32 KB, e-major, group-swizzled
  const int tid  = threadIdx.x;
  const int w    = tid >> 6;
  const int lane = tid & 63;
  const int rg   = lane & 3;
  const int eg   = lane >> 2;      // 0..15
  const int swz  = eg & 7;         // read-side XOR swizzle ( == (e>>2)&7 for e=eg*4+ei )
  const int row0 = blockIdx.x * BR + w * 16 + rg * 4;
  const float* xr = x + (size_t)row0 * DIM;

  // staging: this wave stages chunks ch = w*8 + n (1 KB each = 2 expert-rows of the tile)
  const int ch0 = w * 8;
  const int e_s = 2 * ch0 + (lane >> 5);        // base expert for n=0 (e advances by 2 per n)
  const int g_s = lane & 31;                     // 16B group within expert row

  float acc[4][4];
#pragma unroll
  for (int i = 0; i < 4; ++i)
#pragma unroll
    for (int j = 0; j < 4; ++j) acc[i][j] = 0.f;

  for (int t = 0; t < NT; ++t) {
    const int c0 = t * KT;
    __syncthreads();               // previous tile's reads complete before overwrite
#pragma unroll
    for (int n = 0; n < 8; ++n) {
      const int ch = ch0 + n;
      const int e  = e_s + 2 * n;
      const int sg = g_s ^ ((e >> 2) & 7);       // pre-swizzled SOURCE, linear LDS dest
      async16(wpad + (size_t)e * KP + c0 + sg * 4, (void*)(wt + ch * 256));
    }
    asm volatile("s_waitcnt vmcnt(0)" ::: "memory");
    __syncthreads();

#pragma unroll 4
    for (int c4 = 0; c4 < KT / 4; ++c4) {
      float4 xv[4];
#pragma unroll
      for (int ri = 0; ri < 4; ++ri)
        xv[ri] = *(const float4*)(xr + (size_t)ri * DIM + (c0 + c4 * 4));
#pragma unroll
      for (int ei = 0; ei < 4; ++ei) {
        const float4 wv = *(const float4*)(wt + (eg * 4 + ei) * KT + ((c4 ^ swz) * 4));
#pragma unroll
        for (int ri = 0; ri < 4; ++ri) {
          acc[ri][ei] = fmaf(xv[ri].x, wv.x, acc[ri][ei]);
          acc[ri][ei] = fmaf(xv[ri].y, wv.y, acc[ri][ei]);
          acc[ri][ei] = fmaf(xv[ri].z, wv.z, acc[ri][ei]);
          acc[ri][ei] = fmaf(xv[ri].w, wv.w, acc[ri][ei]);
        }
      }
    }
  }

#pragma unroll
  for (int ri = 0; ri < 4; ++ri) {
    float4 v = make_float4(acc[ri][0], acc[ri][1], acc[ri][2], acc[ri][3]);
    *(float4*)(logits + (size_t)(row0 + ri) * E_N + eg * 4) = v;
  }
}

// ---------------- kernel 2: per-row group-limited top-k routing ----------------
__global__ __launch_bounds__(256) void k_route(const float* __restrict__ logits,
                                               const float* __restrict__ bias,
                                               float* __restrict__ out_w,
                                               float* __restrict__ out_i) {
  __shared__ float bl[E_N];
  if (threadIdx.x < E_N) bl[threadIdx.x] = bias[threadIdx.x];
  __syncthreads();

  const int row = blockIdx.x * 256 + threadIdx.x;      // grid sized exactly
  const float* lp = logits + (size_t)row * E_N;

  float sb[E_N];                                       // sigmoid(logit) + bias
#pragma unroll
  for (int e4 = 0; e4 < 16; ++e4) {
    float4 lv = *(const float4*)(lp + e4 * 4);
    sb[e4 * 4 + 0] = 1.f / (1.f + expf(-lv.x)) + bl[e4 * 4 + 0];
    sb[e4 * 4 + 1] = 1.f / (1.f + expf(-lv.y)) + bl[e4 * 4 + 1];
    sb[e4 * 4 + 2] = 1.f / (1.f + expf(-lv.z)) + bl[e4 * 4 + 2];
    sb[e4 * 4 + 3] = 1.f / (1.f + expf(-lv.w)) + bl[e4 * 4 + 3];
  }

  // group scores: sum of top-2 per group of 8
  float gs[8];
#pragma unroll
  for (int g = 0; g < 8; ++g) {
    float m1 = -__builtin_inff(), m2 = -__builtin_inff();
#pragma unroll
    for (int j = 0; j < 8; ++j) {
      float v = sb[g * 8 + j];
      if (v > m1) { m2 = m1; m1 = v; }
      else if (v > m2) { m2 = v; }
    }
    gs[g] = m1 + m2;
  }

  // top-4 groups (strict > : lower index wins ties, matches lax.top_k)
  unsigned gmask = 0;
#pragma unroll
  for (int tsel = 0; tsel < 4; ++tsel) {
    float best = -__builtin_inff(); int bi = 0;
#pragma unroll
    for (int g = 0; g < 8; ++g) {
      bool avail = ((gmask >> g) & 1u) == 0u;
      if (avail && gs[g] > best) { best = gs[g]; bi = g; }
    }
    gmask |= (1u << bi);
  }

  // taken-mask: pre-ban experts in dropped groups
  unsigned long long tm = 0ull;
#pragma unroll
  for (int g = 0; g < 8; ++g)
    if (((gmask >> g) & 1u) == 0u) tm |= (0xFFull << (8 * g));

  // top-8 experts over allowed groups
  float wv[8]; int io[8]; float wsum = 0.f;
#pragma unroll
  for (int tsel = 0; tsel < 8; ++tsel) {
    float best = -__builtin_inff(); int bi = 0;
#pragma unroll
    for (int e = 0; e < E_N; ++e) {
      bool avail = ((tm >> e) & 1ull) == 0ull;
      if (avail && sb[e] > best) { best = sb[e]; bi = e; }
    }
    tm |= (1ull << bi);
    float sv = best - bl[bi];        // original sigmoid score (bias removed)
    wv[tsel] = sv; io[tsel] = bi; wsum += sv;
  }

  const float scale = 2.5f / wsum;
  float4 w0 = make_float4(wv[0] * scale, wv[1] * scale, wv[2] * scale, wv[3] * scale);
  float4 w1 = make_float4(wv[4] * scale, wv[5] * scale, wv[6] * scale, wv[7] * scale);
  float4 i0 = make_float4((float)io[0], (float)io[1], (float)io[2], (float)io[3]);
  float4 i1 = make_float4((float)io[4], (float)io[5], (float)io[6], (float)io[7]);
  *(float4*)(out_w + (size_t)row * 8)     = w0;
  *(float4*)(out_w + (size_t)row * 8 + 4) = w1;
  *(float4*)(out_i + (size_t)row * 8)     = i0;
  *(float4*)(out_i + (size_t)row * 8 + 4) = i1;
}

extern "C" void kernel_launch(void* const* d_in, const int* in_sizes, int n_in,
                              void* d_out, int out_size, void* d_ws, size_t ws_size,
                              hipStream_t stream) {
  const float* x    = (const float*)d_in[0];
  const float* wgt  = (const float*)d_in[1];
  const float* bias = (const float*)d_in[2];
  float* out    = (float*)d_out;
  float* wpad   = (float*)d_ws;
  float* logits = (float*)d_ws + WS_WPAD_FLOATS;

  k_padw  <<<(E_N * KP) / 256, 256, 0, stream>>>(wgt, wpad);
  k_logits<<<T_TOK / BR,      256, 0, stream>>>(x, wpad, logits);
  k_route <<<T_TOK / 256,     256, 0, stream>>>(logits, bias,
                                                out, out + (size_t)T_TOK * 8);
}